// Round 5
// baseline (523.542 us; speedup 1.0000x reference)
//
#include <hip/hip_runtime.h>

#define N_NODES 10000
#define N_EDGES 640000
#define D_FEAT 128

#define NODES_PER_BLOCK 40
#define NBLOCKS 250            // 250 * 40 = 10000 exactly
#define BLOCK_THREADS 1024
#define WAVES (BLOCK_THREADS / 64)   // 16
#define CHUNK 256                    // edges per wave-iteration (64 lanes x int4)
#define NCHUNKS (N_EDGES / CHUNK)    // 2500 exactly

__global__ __launch_bounds__(BLOCK_THREADS) void fused_mean_agg_kernel(
    const float* __restrict__ x,
    const int* __restrict__ src,
    const int* __restrict__ dst,
    const float* __restrict__ deg,
    float* __restrict__ out) {
    __shared__ float acc[NODES_PER_BLOCK][D_FEAT];   // 20 KB

    const int tid = threadIdx.x;

    // Zero LDS accumulators.
    #pragma unroll
    for (int i = tid; i < NODES_PER_BLOCK * D_FEAT; i += BLOCK_THREADS)
        ((float*)acc)[i] = 0.0f;
    __syncthreads();

    const int node_base = blockIdx.x * NODES_PER_BLOCK;
    const int w = tid >> 6;
    const int lane = tid & 63;

    // Scan all edges; each wave takes 256-edge chunks round-robin.
    for (int c = w; c < NCHUNKS; c += WAVES) {
        const int e0 = c * CHUNK + lane * 4;
        const int4 d4 = *reinterpret_cast<const int4*>(&dst[e0]);

        #pragma unroll
        for (int k = 0; k < 4; ++k) {
            const int d = (k == 0) ? d4.x : (k == 1) ? d4.y : (k == 2) ? d4.z : d4.w;
            const int loc = d - node_base;
            const bool m = ((unsigned)loc < (unsigned)NODES_PER_BLOCK);
            int s = 0;
            if (m) s = src[e0 + k];             // predicated scattered load, low volume
            unsigned long long mask = __ballot(m);
            while (mask) {
                const int l = __ffsll((unsigned long long)mask) - 1;
                mask &= mask - 1;
                const int ss = __shfl(s, l);
                const int ln = __shfl(loc, l);
                const float* xr = &x[(size_t)ss * D_FEAT];
                const float v0 = xr[lane];        // coalesced 256B
                const float v1 = xr[64 + lane];   // coalesced 256B
                atomicAdd(&acc[ln][lane], v0);        // ds_add_f32, bank = lane%32, 2-way (free)
                atomicAdd(&acc[ln][64 + lane], v1);
            }
        }
    }
    __syncthreads();

    // Normalize by degree and write each output row once (float4, coalesced).
    const int total4 = NODES_PER_BLOCK * (D_FEAT / 4);    // 1280
    for (int i = tid; i < total4; i += BLOCK_THREADS) {
        const int ln = i >> 5;               // /32
        const int f = (i & 31) << 2;         // feature offset
        const int node = node_base + ln;
        const float inv = 1.0f / deg[node];
        float4 v = *reinterpret_cast<const float4*>(&acc[ln][f]);
        v.x *= inv; v.y *= inv; v.z *= inv; v.w *= inv;
        *reinterpret_cast<float4*>(&out[(size_t)node * D_FEAT + f]) = v;
    }
}

extern "C" void kernel_launch(void* const* d_in, const int* in_sizes, int n_in,
                              void* d_out, int out_size, void* d_ws, size_t ws_size,
                              hipStream_t stream) {
    const float* x   = (const float*)d_in[0];
    const int*   ei  = (const int*)d_in[1];   // [2, N_EDGES] flat: src row, dst row
    const float* deg = (const float*)d_in[2];
    float* out = (float*)d_out;

    const int* src = ei;
    const int* dst = ei + N_EDGES;

    fused_mean_agg_kernel<<<NBLOCKS, BLOCK_THREADS, 0, stream>>>(x, src, dst, deg, out);
}

// Round 6
// 140.527 us; speedup vs baseline: 3.7256x; 3.7256x over previous
//
#include <hip/hip_runtime.h>

#define N_NODES 10000
#define N_EDGES 640000
#define D_FEAT 128
#define NGROUPS 8
#define NODES_PER_GROUP (N_NODES / NGROUPS)   // 1250

// ---- ws layout (bytes) ----
// offsets : [0, 40000)        int[10000]
// cursors : [40064, 80064)    int[10000]
// csr_src : [80128, ...)      int[<=650000]  (sum(max(count,1)) <= 650000)
#define WS_OFFSETS 0
#define WS_CURSORS 40064
#define WS_CSR     80128

// Single-block exclusive scan of (int)deg -> offsets, cursors. 10 elems/thread.
__global__ __launch_bounds__(1024) void scan_kernel(
    const float* __restrict__ deg,
    int* __restrict__ offsets,
    int* __restrict__ cursors) {
    __shared__ int lds[1024];
    const int t = threadIdx.x;
    int local[10];
    int s = 0;
    #pragma unroll
    for (int j = 0; j < 10; ++j) {
        int i = t * 10 + j;
        int c = (i < N_NODES) ? (int)deg[i] : 0;
        local[j] = c;
        s += c;
    }
    lds[t] = s;
    __syncthreads();
    for (int off = 1; off < 1024; off <<= 1) {
        int v = (t >= off) ? lds[t - off] : 0;
        __syncthreads();
        lds[t] += v;
        __syncthreads();
    }
    int p = lds[t] - s;   // exclusive prefix of this thread's chunk
    #pragma unroll
    for (int j = 0; j < 10; ++j) {
        int i = t * 10 + j;
        if (i < N_NODES) { offsets[i] = p; cursors[i] = p; }
        p += local[j];
    }
}

// Group-partitioned fill: blocks with b%8==k handle ONLY dst in [k*1250,(k+1)*1250),
// so each csr slice (~320KB) is written by one block-group (XCD-local writes if
// blockIdx%8 tracks XCD; correct regardless). Each group scans all edges.
#define FILL_BLOCKS 2048
#define FILL_THREADS 256
__global__ __launch_bounds__(FILL_THREADS) void fill_kernel(
    const int* __restrict__ src,
    const int* __restrict__ dst,
    int* __restrict__ cursors,
    int* __restrict__ csr) {
    const int b = blockIdx.x;
    const int k = b & 7;
    const int r = b >> 3;                       // rank in group, 0..255
    const int lo = k * NODES_PER_GROUP;
    const int hi = lo + NODES_PER_GROUP;
    const int tg = r * FILL_THREADS + threadIdx.x;   // 0..65535 within group
    const int NV = N_EDGES / 4;                 // 160000 int4's
    for (int v = tg; v < NV; v += 65536) {
        const int4 d4 = reinterpret_cast<const int4*>(dst)[v];
        const int e0 = v << 2;
        #pragma unroll
        for (int kk = 0; kk < 4; ++kk) {
            const int d = (kk == 0) ? d4.x : (kk == 1) ? d4.y : (kk == 2) ? d4.z : d4.w;
            if (d >= lo && d < hi) {
                int pos = atomicAdd(&cursors[d], 1);
                csr[pos] = src[e0 + kk];
            }
        }
    }
}

// Gather: 32 lanes per node, 8 nodes per 256-thread block; node grouping matches
// fill's %8 partition so csr reads hit the same L2 slice that fill wrote.
#define GATHER_BPG 157                          // ceil(1250/8)
#define GATHER_BLOCKS (GATHER_BPG * NGROUPS)    // 1256
__global__ __launch_bounds__(256) void gather_kernel(
    const float* __restrict__ x,
    const int* __restrict__ offsets,
    const int* __restrict__ cursors,   // post-fill: exact segment ends
    const int* __restrict__ csr,
    const float* __restrict__ deg,
    float* __restrict__ out) {
    const int b = blockIdx.x;
    const int k = b & 7;
    const int r = b >> 3;
    const int g = threadIdx.x >> 5;
    const int lane = threadIdx.x & 31;
    const int nig = r * 8 + g;
    if (nig >= NODES_PER_GROUP) return;
    const int node = k * NODES_PER_GROUP + nig;
    const int f = lane << 2;

    int j = offsets[node];
    const int end = cursors[node];

    float4 acc = make_float4(0.f, 0.f, 0.f, 0.f);
    for (; j + 4 <= end; j += 4) {
        int s0 = csr[j + 0];
        int s1 = csr[j + 1];
        int s2 = csr[j + 2];
        int s3 = csr[j + 3];
        float4 a = *reinterpret_cast<const float4*>(&x[(size_t)s0 * D_FEAT + f]);
        float4 bb = *reinterpret_cast<const float4*>(&x[(size_t)s1 * D_FEAT + f]);
        float4 c = *reinterpret_cast<const float4*>(&x[(size_t)s2 * D_FEAT + f]);
        float4 d = *reinterpret_cast<const float4*>(&x[(size_t)s3 * D_FEAT + f]);
        acc.x += a.x + bb.x + c.x + d.x;
        acc.y += a.y + bb.y + c.y + d.y;
        acc.z += a.z + bb.z + c.z + d.z;
        acc.w += a.w + bb.w + c.w + d.w;
    }
    for (; j < end; ++j) {
        int s = csr[j];
        float4 a = *reinterpret_cast<const float4*>(&x[(size_t)s * D_FEAT + f]);
        acc.x += a.x; acc.y += a.y; acc.z += a.z; acc.w += a.w;
    }

    const float inv = 1.0f / deg[node];
    float4 rv = make_float4(acc.x * inv, acc.y * inv, acc.z * inv, acc.w * inv);
    *reinterpret_cast<float4*>(&out[(size_t)node * D_FEAT + f]) = rv;
}

extern "C" void kernel_launch(void* const* d_in, const int* in_sizes, int n_in,
                              void* d_out, int out_size, void* d_ws, size_t ws_size,
                              hipStream_t stream) {
    const float* x   = (const float*)d_in[0];
    const int*   ei  = (const int*)d_in[1];   // [2, N_EDGES] flat: src row, dst row
    const float* deg = (const float*)d_in[2];
    float* out = (float*)d_out;

    const int* src = ei;
    const int* dst = ei + N_EDGES;

    char* ws = (char*)d_ws;
    int* offsets = (int*)(ws + WS_OFFSETS);
    int* cursors = (int*)(ws + WS_CURSORS);
    int* csr     = (int*)(ws + WS_CSR);

    scan_kernel<<<1, 1024, 0, stream>>>(deg, offsets, cursors);
    fill_kernel<<<FILL_BLOCKS, FILL_THREADS, 0, stream>>>(src, dst, cursors, csr);
    gather_kernel<<<GATHER_BLOCKS, 256, 0, stream>>>(x, offsets, cursors, csr, deg, out);
}